// Round 13
// baseline (303.886 us; speedup 1.0000x reference)
//
#include <hip/hip_runtime.h>
#include <stdint.h>

// Problem constants (fixed by the reference): B=8, H=W=64, C=256
#define CC 256
#define NN 4096           // H*W
#define MM 2048           // NN/2 (pooled)
#define BB 8
#define NROWS (BB*NN)     // 32768 query rows
#define PROWS (BB*MM)     // 16384 pooled rows

typedef __attribute__((ext_vector_type(8))) short    short8;   // 8 bf16
typedef __attribute__((ext_vector_type(8))) _Float16 half8;    // 8 fp16
typedef __attribute__((ext_vector_type(4))) float    float4v;

__device__ __forceinline__ unsigned short f2bf(float f) {
    unsigned int u = __float_as_uint(f);
    u += 0x7fffu + ((u >> 16) & 1u);
    return (unsigned short)(u >> 16);
}
__device__ __forceinline__ float bf2f(unsigned short h) {
    return __uint_as_float(((unsigned int)h) << 16);
}
__device__ __forceinline__ unsigned short f2h(float f) {
    union { _Float16 h; unsigned short u; } cv; cv.h = (_Float16)f; return cv.u;
}
__device__ __forceinline__ float h2f(unsigned short u) {
    union { _Float16 h; unsigned short u; } cv; cv.u = u; return (float)cv.h;
}

// ---------------------------------------------------------------------------
// xsplit: x (fp32) -> x_hi/x_lo (bf16 split), elementwise, once.
// ---------------------------------------------------------------------------
__global__ __launch_bounds__(256) void xsplit_kernel(
    const float* __restrict__ x,
    unsigned short* __restrict__ x_hi,
    unsigned short* __restrict__ x_lo)
{
    const size_t i = ((size_t)blockIdx.x*256 + threadIdx.x) * 8;
    float4v a0 = *(const float4v*)(x + i);
    float4v a1 = *(const float4v*)(x + i + 4);
    short8 h, l;
    #pragma unroll
    for (int j = 0; j < 4; ++j) {
        unsigned short h0 = f2bf(a0[j]);
        h[j]   = (short)h0; l[j]   = (short)f2bf(a0[j] - bf2f(h0));
        unsigned short h1 = f2bf(a1[j]);
        h[4+j] = (short)h1; l[4+j] = (short)f2bf(a1[j] - bf2f(h1));
    }
    *(short8*)(x_hi + i) = h;
    *(short8*)(x_lo + i) = l;
}

// ---------------------------------------------------------------------------
// wsplit: transpose + bf16 hi/lo split the three 256x256 weights once.
// ---------------------------------------------------------------------------
__global__ void wsplit_kernel(const float* __restrict__ w_theta,
                              const float* __restrict__ w_phi,
                              const float* __restrict__ w_g,
                              unsigned short* __restrict__ wT_hi,
                              unsigned short* __restrict__ wT_lo)
{
    __shared__ float tile[64][65];
    const int widx = blockIdx.z;
    const int kt = blockIdx.x, ct = blockIdx.y;
    const float* w = (widx == 0) ? w_theta : (widx == 1) ? w_phi : w_g;
    const int t  = threadIdx.x;
    const int tc = t & 63, tr = t >> 6;
    #pragma unroll
    for (int i = 0; i < 16; ++i) {
        const int lk = tr*16 + i;
        tile[lk][tc] = w[(size_t)(kt*64 + lk)*CC + ct*64 + tc];
    }
    __syncthreads();
    #pragma unroll
    for (int i = 0; i < 16; ++i) {
        const int lc = tr*16 + i;
        float v = tile[tc][lc];
        const int c = ct*64 + lc, k = kt*64 + tc;
        unsigned short hh = f2bf(v);
        size_t o = ((size_t)widx*CC + c)*CC + k;
        wT_hi[o] = hh;
        wT_lo[o] = f2bf(v - bf2f(hh));
    }
}

// ---------------------------------------------------------------------------
// proj_kernel v7 (verified in R9): g in MFMA B-FRAGMENT ORDER; theta/phi as v6.
// ---------------------------------------------------------------------------
__global__ __launch_bounds__(256, 4) void proj_kernel(
    const unsigned short* __restrict__ x_hi,
    const unsigned short* __restrict__ x_lo,
    const unsigned short* __restrict__ wT_hi,
    const unsigned short* __restrict__ wT_lo,
    unsigned short* __restrict__ th,
    unsigned short* __restrict__ ph,
    unsigned short* __restrict__ g_f)
{
    __shared__ unsigned short wt_hi[64*136];   // [64 cols][128 k + pad]
    __shared__ unsigned short wt_lo[64*136];

    const int tid  = threadIdx.x;
    const int rb   = blockIdx.x & 511;         // row-block (XCD = rb%8)
    const int cv   = blockIdx.x >> 9;          // 0..11 col-variant
    const int r0   = rb * 64;
    const int widx = cv >> 2;
    const int wc0  = (cv & 3) * 64;
    const unsigned short* wThp = wT_hi + ((size_t)widx*CC + wc0)*CC;
    const unsigned short* wTlp = wT_lo + ((size_t)widx*CC + wc0)*CC;
    const bool split3 = (widx < 2);            // theta/phi 3-pass; g 1-pass

    const int wv   = tid >> 6;
    const int lane = tid & 63;
    const int quad = lane >> 4;
    const int l15  = lane & 15;
    const int arow = r0 + wv*16 + l15;
    const unsigned short* axh = x_hi + (size_t)arow*CC + quad*8;
    const unsigned short* axl = x_lo + (size_t)arow*CC + quad*8;

    float4v acc[4];
    #pragma unroll
    for (int nf = 0; nf < 4; ++nf) acc[nf] = (float4v){0.f,0.f,0.f,0.f};

    for (int h = 0; h < 2; ++h) {
        __syncthreads();
        {   // stage pre-split W^T tile [64 cols][128 k] (pure copy)
            const int j    = tid & 63;
            const int kseg = tid >> 6;
            const size_t base = (size_t)j*CC + h*128 + kseg*32;
            const unsigned short* sh = wThp + base;
            unsigned short* dh = &wt_hi[j*136 + kseg*32];
            #pragma unroll
            for (int u = 0; u < 4; ++u)
                *(uint4*)(dh + u*8) = *(const uint4*)(sh + u*8);
            if (split3) {
                const unsigned short* sl = wTlp + base;
                unsigned short* dl = &wt_lo[j*136 + kseg*32];
                #pragma unroll
                for (int u = 0; u < 4; ++u)
                    *(uint4*)(dl + u*8) = *(const uint4*)(sl + u*8);
            }
        }
        __syncthreads();

        #pragma unroll
        for (int ks = 0; ks < 4; ++ks) {
            short8 a_hi = *(const short8*)(axh + h*128 + ks*32);
            short8 a_lo;
            if (split3) a_lo = *(const short8*)(axl + h*128 + ks*32);
            #pragma unroll
            for (int nf = 0; nf < 4; ++nf) {
                const int wrow = nf*16 + l15;
                short8 b_hi = *(const short8*)&wt_hi[wrow*136 + ks*32 + quad*8];
                acc[nf] = __builtin_amdgcn_mfma_f32_16x16x32_bf16(a_hi, b_hi, acc[nf], 0,0,0);
                if (split3) {
                    short8 b_lo = *(const short8*)&wt_lo[wrow*136 + ks*32 + quad*8];
                    acc[nf] = __builtin_amdgcn_mfma_f32_16x16x32_bf16(a_hi, b_lo, acc[nf], 0,0,0);
                    acc[nf] = __builtin_amdgcn_mfma_f32_16x16x32_bf16(a_lo, b_hi, acc[nf], 0,0,0);
                }
            }
        }
    }

    const int rowbase = r0 + wv*16 + quad*4;
    if (widx == 0) {                           // theta: unpooled, fp16 single
        #pragma unroll
        for (int nf = 0; nf < 4; ++nf) {
            const int c = wc0 + nf*16 + l15;
            #pragma unroll
            for (int r = 0; r < 4; ++r)
                th[(size_t)(rowbase + r)*CC + c] = f2h(acc[nf][r]);
        }
    } else if (widx == 1) {                    // phi: pool row pairs, fp16
        #pragma unroll
        for (int nf = 0; nf < 4; ++nf) {
            const int c = wc0 + nf*16 + l15;
            #pragma unroll
            for (int rp = 0; rp < 2; ++rp) {
                float v = fmaxf(acc[nf][2*rp], acc[nf][2*rp+1]);
                const int prow = rowbase/2 + rp;   // rowbase even -> exact
                ph[(size_t)prow*CC + c] = f2h(v);
            }
        }
    } else {                                   // g: pool, bf16, FRAG ORDER
        #pragma unroll
        for (int nf = 0; nf < 4; ++nf) {
            const int c = wc0 + nf*16 + l15;
            const int ct = c >> 4;             // col-tile 0..15
            const int c15 = c & 15;
            #pragma unroll
            for (int rp = 0; rp < 2; ++rp) {
                float v = fmaxf(acc[nf][2*rp], acc[nf][2*rp+1]);
                const int prow = rowbase/2 + rp;
                const int b  = prow >> 11;
                const int m  = prow & 2047;    // key index within batch
                const int kt = m >> 5;         // 32-key tile
                const int km = m & 31;
                const int lane_t = (km >> 3)*16 + c15;
                const int j = km & 7;
                g_f[(((size_t)(b*64 + kt)*16 + ct)*64 + lane_t)*8 + j] = f2bf(v);
            }
        }
    }
}

// ---------------------------------------------------------------------------
// phimean: per-batch column mean of phi; 512 blocks (32 rows each).
// ---------------------------------------------------------------------------
__global__ void phimean_kernel(const unsigned short* __restrict__ ph,
                               float* __restrict__ phbar)
{
    const int b = blockIdx.x >> 6, chunk = blockIdx.x & 63;
    const int c = threadIdx.x;
    const size_t base = ((size_t)b*MM + chunk*32)*CC + c;
    float s = 0.f;
    for (int r = 0; r < 32; ++r) s += h2f(ph[base + (size_t)r*CC]);
    atomicAdd(&phbar[b*CC + c], s * (1.0f/MM));
}

// ---------------------------------------------------------------------------
// attn_kernel v17: v15's EXACT inner loop (verified 103us: coalesced staging,
// frag-ordered g, 2 barriers, single s_p) + v12's EXACT k-split skeleton
// (verified correct at R8): kh=0/1 handle 1024 keys = 32 iters each,
// partial O (f32, undivided) + partial l out; combine finishes.
//  Rationale: R9/R11 proved the v12-era anti-scaling was VMEM-gather
//  contention (per-block-iter 2383->3400cy at 2x blocks). Gathers are now
//  fixed; retry the split at identical per-wave per-iter work ->
//  4 blocks/CU = 16 waves/CU to overlap the dependent S-chain latency.
//  LDS 38.9KB (no s_l), launch_bounds(256,4): VGPR cap 128 (v15 uses 84).
// ---------------------------------------------------------------------------
__global__ __launch_bounds__(256, 4) void attn_kernel(
    const unsigned short* __restrict__ th,
    const unsigned short* __restrict__ ph,
    const unsigned short* __restrict__ g_f,
    const float* __restrict__ phbar,
    float* __restrict__ o0,
    float* __restrict__ o1,
    float* __restrict__ lb)
{
    __shared__ unsigned short s_ph[2][32*264]; // phi dbuf fp16, padded rows
    __shared__ unsigned short s_p[4][16*40];   // P: [src wave][16 q][32 k pad 40]

    const int tid  = threadIdx.x;
    const int bb   = blockIdx.x & 7;           // batch == XCD (L2 affinity)
    const int rest = blockIdx.x >> 3;          // 0..127
    const int qt   = rest >> 1;                // q-tile within batch 0..63
    const int kh   = rest & 1;                 // key half 0/1
    const int q0   = bb*NN + qt*64;
    const int b    = bb;
    const int wv   = tid >> 6;
    const int lane = tid & 63;
    const int quad = lane >> 4;
    const int l15  = lane & 15;

    // coalesced staging (v15): instr u, thread tid owns chunk u*256+tid of
    // the 16KB key-tile; this block's tiles start at key kh*1024.
    const size_t phbase = (size_t)b * MM * CC;
    const unsigned short* stsrc = ph + phbase + (size_t)kh*1024*CC + (size_t)tid*8;
    const int ldsbase = (tid >> 5)*264 + (tid & 31)*8;

    // theta A-frags (fp16, single) for this wave's 16 rows
    half8 t_hi[8];
    {
        const unsigned short* bh = th + (size_t)(q0 + wv*16 + l15)*CC;
        #pragma unroll
        for (int ks = 0; ks < 8; ++ks)
            t_hi[ks] = *(const half8*)(bh + ks*32 + quad*8);
    }

    // per-row shift = theta . phibar (+128), moved to C-layout rows via shfl
    float sh128[4];
    {
        float sp = 0.f;
        #pragma unroll
        for (int ks = 0; ks < 8; ++ks) {
            const int k0 = ks*32 + quad*8;
            float4v m0 = *(const float4v*)&phbar[b*CC + k0];
            float4v m1 = *(const float4v*)&phbar[b*CC + k0 + 4];
            #pragma unroll
            for (int j = 0; j < 4; ++j) {
                sp += (float)t_hi[ks][j]   * m0[j];
                sp += (float)t_hi[ks][4+j] * m1[j];
            }
        }
        sp += __shfl_xor(sp, 16);
        sp += __shfl_xor(sp, 32);
        #pragma unroll
        for (int r = 0; r < 4; ++r)
            sh128[r] = __shfl(sp, quad*4 + r) + 128.f;
    }

    // O: all 64 block-queries x this wave's 64-col strip (partial, 1024 keys)
    float4v O[4][4];
    #pragma unroll
    for (int rt = 0; rt < 4; ++rt)
        #pragma unroll
        for (int ct = 0; ct < 4; ++ct) O[rt][ct] = (float4v){0.f,0.f,0.f,0.f};
    float4v accl = (float4v){0.f,0.f,0.f,0.f};

    short8 ones;
    #pragma unroll
    for (int j = 0; j < 8; ++j) ones[j] = (short)0x3F80;   // bf16 1.0

    // frag-ordered g base (R9): per-lane 16B inside each 1KB frag
    const unsigned short* glf = g_f + (size_t)b*MM*CC + (size_t)lane*8;

    // prologue: stage tile 0 into buf 0 (coalesced)
    {
        #pragma unroll
        for (int u = 0; u < 4; ++u)
            *(uint4*)(&s_ph[0][ldsbase + u*2112]) =
                *(const uint4*)(stsrc + u*2048);
    }
    __syncthreads();

    for (int kt = 0; kt < 32; ++kt) {
        const int cur = kt & 1;

        // issue next-tile phi loads early (coalesced)
        uint4 stg[4];
        if (kt < 31) {
            const unsigned short* sn = stsrc + (size_t)(kt + 1)*8192;
            #pragma unroll
            for (int u = 0; u < 4; ++u)
                stg[u] = *(const uint4*)(sn + u*2048);
        }
        // this tile's g frags: ONE coalesced b128 per col-tile
        short8 gf[4];
        #pragma unroll
        for (int ct = 0; ct < 4; ++ct)
            gf[ct] = *(const short8*)(glf + (size_t)((kh*32 + kt)*16 + wv*4 + ct)*512);

        // S = theta @ phi^T, 1-pass fp16, from current buffer
        float4v S0 = (float4v){0.f,0.f,0.f,0.f};
        float4v S1 = (float4v){0.f,0.f,0.f,0.f};
        #pragma unroll
        for (int ks = 0; ks < 8; ++ks) {
            half8 b0 = *(const half8*)&s_ph[cur][( 0 + l15)*264 + ks*32 + quad*8];
            half8 b1 = *(const half8*)&s_ph[cur][(16 + l15)*264 + ks*32 + quad*8];
            S0 = __builtin_amdgcn_mfma_f32_16x16x32_f16(t_hi[ks], b0, S0, 0,0,0);
            S1 = __builtin_amdgcn_mfma_f32_16x16x32_f16(t_hi[ks], b1, S1, 0,0,0);
        }

        // p = exp(clamp(S - shift, -85, 85)) -> bf16 into shared P
        unsigned short* pw = &s_p[wv][0];
        #pragma unroll
        for (int r = 0; r < 4; ++r) {
            float a0 = fminf(fmaxf(S0[r] - sh128[r], -85.f), 85.f);
            float a1 = fminf(fmaxf(S1[r] - sh128[r], -85.f), 85.f);
            pw[(quad*4 + r)*40 + l15]      = f2bf(__expf(a0));
            pw[(quad*4 + r)*40 + 16 + l15] = f2bf(__expf(a1));
        }
        asm volatile("s_waitcnt lgkmcnt(0)" ::: "memory");
        // own-row l accumulation (own s_p region; intra-wave wait only)
        short8 pown = *(const short8*)&s_p[wv][l15*40 + quad*8];
        accl = __builtin_amdgcn_mfma_f32_16x16x32_bf16(pown, ones, accl, 0,0,0);

        // write staged phi into the other buffer before the barrier
        if (kt < 31) {
            #pragma unroll
            for (int u = 0; u < 4; ++u)
                *(uint4*)(&s_ph[cur ^ 1][ldsbase + u*2112]) = stg[u];
        }
        __syncthreads();                       // P visible; next phi staged

        // PV: O[all 64 q][this wave's 64 cols] += P @ g
        #pragma unroll
        for (int rt = 0; rt < 4; ++rt) {
            short8 pA = *(const short8*)&s_p[rt][l15*40 + quad*8];
            #pragma unroll
            for (int ct = 0; ct < 4; ++ct)
                O[rt][ct] = __builtin_amdgcn_mfma_f32_16x16x32_bf16(pA, gf[ct], O[rt][ct], 0,0,0);
        }
        __syncthreads();                       // s_p reusable next iter
    }

    // partial l: wave wv owns rows wv*16+quad*4+r (lane l15==0 holds sums)
    float* od = (kh == 0) ? o0 : o1;
    if (l15 == 0) {
        #pragma unroll
        for (int r = 0; r < 4; ++r)
            lb[(size_t)kh*NROWS + q0 + wv*16 + quad*4 + r] = accl[r];
    }

    // partial O store (undivided, f32): wave wv writes cols wv*64..wv*64+63
    #pragma unroll
    for (int rt = 0; rt < 4; ++rt) {
        #pragma unroll
        for (int r = 0; r < 4; ++r) {
            const int row = q0 + rt*16 + quad*4 + r;
            #pragma unroll
            for (int ct = 0; ct < 4; ++ct) {
                const int c = wv*64 + ct*16 + l15;
                od[(size_t)row*CC + c] = O[rt][ct][r];
            }
        }
    }
}

// ---------------------------------------------------------------------------
// combine (verified R8): out = x + (O0 + O1) / (l0 + l1). O1 is in `out`.
// ---------------------------------------------------------------------------
__global__ __launch_bounds__(256) void combine_kernel(
    const float* __restrict__ x,
    const float* __restrict__ o0,
    const float* __restrict__ lb,
    float* __restrict__ out)
{
    const size_t i = ((size_t)blockIdx.x*256 + threadIdx.x) * 8;
    const int row = (int)(i >> 8);
    const float rl = 1.0f / (lb[row] + lb[NROWS + row]);
    float4v x0 = *(const float4v*)(x + i);
    float4v x1 = *(const float4v*)(x + i + 4);
    float4v a0 = *(const float4v*)(o0 + i);
    float4v a1 = *(const float4v*)(o0 + i + 4);
    float4v b0 = *(const float4v*)(out + i);
    float4v b1 = *(const float4v*)(out + i + 4);
    float4v r0, r1;
    #pragma unroll
    for (int j = 0; j < 4; ++j) {
        r0[j] = x0[j] + (a0[j] + b0[j]) * rl;
        r1[j] = x1[j] + (a1[j] + b1[j]) * rl;
    }
    *(float4v*)(out + i)     = r0;
    *(float4v*)(out + i + 4) = r1;
}

// ---------------------------------------------------------------------------
extern "C" void kernel_launch(void* const* d_in, const int* in_sizes, int n_in,
                              void* d_out, int out_size, void* d_ws, size_t ws_size,
                              hipStream_t stream) {
    const float* x       = (const float*)d_in[0];
    const float* w_theta = (const float*)d_in[1];
    const float* w_phi   = (const float*)d_in[2];
    const float* w_g     = (const float*)d_in[3];
    float* out = (float*)d_out;

    // workspace (~51.2 MB)
    unsigned short* th    = (unsigned short*)d_ws;                 // fp16 16.78 MB
    unsigned short* ph    = th    + (size_t)NROWS*CC;              // fp16  8.39 MB
    unsigned short* g_f   = ph    + (size_t)PROWS*CC;              // bf16  8.39 MB (frag order)
    unsigned short* x_hi  = g_f   + (size_t)PROWS*CC;              // bf16  8.39 MB
    unsigned short* x_lo  = x_hi  + (size_t)NROWS*CC;              // bf16  8.39 MB
    unsigned short* wT_hi = x_lo  + (size_t)NROWS*CC;              // bf16  0.39 MB
    unsigned short* wT_lo = wT_hi + (size_t)3*CC*CC;               // bf16  0.39 MB
    float*          phbar = (float*)(wT_lo + (size_t)3*CC*CC);     // fp32  8 KB

    // overlays (dead after proj): O0 partial over x_hi+x_lo (33.55 MB f32);
    // l partials (2 x 128 KB) over wT_hi/wT_lo (0.78 MB).
    float* o0 = (float*)x_hi;
    float* lb = (float*)wT_hi;

    hipMemsetAsync(phbar, 0, BB*CC*sizeof(float), stream);
    xsplit_kernel<<<NROWS*CC/8/256, 256, 0, stream>>>(x, x_hi, x_lo);
    wsplit_kernel<<<dim3(4,4,3), 256, 0, stream>>>(w_theta, w_phi, w_g, wT_hi, wT_lo);
    proj_kernel<<<6144, 256, 0, stream>>>(x_hi, x_lo, wT_hi, wT_lo, th, ph, g_f);
    phimean_kernel<<<512, 256, 0, stream>>>(ph, phbar);
    attn_kernel<<<NROWS/64*2, 256, 0, stream>>>(th, ph, g_f, phbar, o0, out, lb);
    combine_kernel<<<NROWS*CC/2048, 256, 0, stream>>>(x, o0, lb, out);
}

// Round 14
// 259.216 us; speedup vs baseline: 1.1723x; 1.1723x over previous
//
#include <hip/hip_runtime.h>
#include <stdint.h>

// Problem constants (fixed by the reference): B=8, H=W=64, C=256
#define CC 256
#define NN 4096           // H*W
#define MM 2048           // NN/2 (pooled)
#define BB 8
#define NROWS (BB*NN)     // 32768 query rows
#define PROWS (BB*MM)     // 16384 pooled rows

typedef __attribute__((ext_vector_type(8))) short    short8;   // 8 bf16
typedef __attribute__((ext_vector_type(8))) _Float16 half8;    // 8 fp16
typedef __attribute__((ext_vector_type(4))) float    float4v;

__device__ __forceinline__ unsigned short f2bf(float f) {
    unsigned int u = __float_as_uint(f);
    u += 0x7fffu + ((u >> 16) & 1u);
    return (unsigned short)(u >> 16);
}
__device__ __forceinline__ float bf2f(unsigned short h) {
    return __uint_as_float(((unsigned int)h) << 16);
}
__device__ __forceinline__ unsigned short f2h(float f) {
    union { _Float16 h; unsigned short u; } cv; cv.h = (_Float16)f; return cv.u;
}
__device__ __forceinline__ float h2f(unsigned short u) {
    union { _Float16 h; unsigned short u; } cv; cv.u = u; return (float)cv.h;
}

// ---------------------------------------------------------------------------
// xsplit v2: x (fp32) -> x_hi/x_lo in MFMA A-FRAGMENT ORDER.
//   frag f = row-tile rt (16 rows) x ks (32 k): 1KB, lane (quad,l15) holds
//   row l15, k = ks*32 + quad*8 .. +7.  Writes perfectly coalesced (1KB/
//   wave-instr); reads are 16x128B runs (L2-absorbed, one-shot).
//   Purpose: proj's per-MFMA A-loads become single coalesced b128s
//   (was 16-line gathers -- the R9/R11 win class, 3rd application).
// ---------------------------------------------------------------------------
__global__ __launch_bounds__(256) void xsplit_kernel(
    const float* __restrict__ x,
    unsigned short* __restrict__ x_hi,
    unsigned short* __restrict__ x_lo)
{
    const int rt   = blockIdx.x;               // row-tile 0..2047
    const int tid  = threadIdx.x;
    const int wv   = tid >> 6;
    const int lane = tid & 63;
    const int quad = lane >> 4;
    const int l15  = lane & 15;
    const int row  = rt*16 + l15;
    #pragma unroll
    for (int kk = 0; kk < 2; ++kk) {
        const int ks = wv*2 + kk;              // 0..7
        const int k0 = ks*32 + quad*8;
        float4v a0 = *(const float4v*)(x + (size_t)row*CC + k0);
        float4v a1 = *(const float4v*)(x + (size_t)row*CC + k0 + 4);
        short8 h, l;
        #pragma unroll
        for (int j = 0; j < 4; ++j) {
            unsigned short h0 = f2bf(a0[j]);
            h[j]   = (short)h0; l[j]   = (short)f2bf(a0[j] - bf2f(h0));
            unsigned short h1 = f2bf(a1[j]);
            h[4+j] = (short)h1; l[4+j] = (short)f2bf(a1[j] - bf2f(h1));
        }
        const size_t o = ((size_t)rt*8 + ks)*512 + (size_t)lane*8;
        *(short8*)(x_hi + o) = h;
        *(short8*)(x_lo + o) = l;
    }
}

// ---------------------------------------------------------------------------
// wsplit: transpose + bf16 hi/lo split the three 256x256 weights once.
// ---------------------------------------------------------------------------
__global__ void wsplit_kernel(const float* __restrict__ w_theta,
                              const float* __restrict__ w_phi,
                              const float* __restrict__ w_g,
                              unsigned short* __restrict__ wT_hi,
                              unsigned short* __restrict__ wT_lo)
{
    __shared__ float tile[64][65];
    const int widx = blockIdx.z;
    const int kt = blockIdx.x, ct = blockIdx.y;
    const float* w = (widx == 0) ? w_theta : (widx == 1) ? w_phi : w_g;
    const int t  = threadIdx.x;
    const int tc = t & 63, tr = t >> 6;
    #pragma unroll
    for (int i = 0; i < 16; ++i) {
        const int lk = tr*16 + i;
        tile[lk][tc] = w[(size_t)(kt*64 + lk)*CC + ct*64 + tc];
    }
    __syncthreads();
    #pragma unroll
    for (int i = 0; i < 16; ++i) {
        const int lc = tr*16 + i;
        float v = tile[tc][lc];
        const int c = ct*64 + lc, k = kt*64 + tc;
        unsigned short hh = f2bf(v);
        size_t o = ((size_t)widx*CC + c)*CC + k;
        wT_hi[o] = hh;
        wT_lo[o] = f2bf(v - bf2f(hh));
    }
}

// ---------------------------------------------------------------------------
// proj_kernel v9: v7 (R9-verified) with A-loads from FRAG-ORDERED x_hi/x_lo:
// one coalesced 1KB b128 per A-frag (was a 16-line-run gather, ~96/block).
// Same values, same MFMA order -> numerics identical.
// ---------------------------------------------------------------------------
__global__ __launch_bounds__(256, 4) void proj_kernel(
    const unsigned short* __restrict__ x_hi,
    const unsigned short* __restrict__ x_lo,
    const unsigned short* __restrict__ wT_hi,
    const unsigned short* __restrict__ wT_lo,
    unsigned short* __restrict__ th,
    unsigned short* __restrict__ ph,
    unsigned short* __restrict__ g_f)
{
    __shared__ unsigned short wt_hi[64*136];   // [64 cols][128 k + pad]
    __shared__ unsigned short wt_lo[64*136];

    const int tid  = threadIdx.x;
    const int rb   = blockIdx.x & 511;         // row-block (XCD = rb%8)
    const int cv   = blockIdx.x >> 9;          // 0..11 col-variant
    const int r0   = rb * 64;
    const int widx = cv >> 2;
    const int wc0  = (cv & 3) * 64;
    const unsigned short* wThp = wT_hi + ((size_t)widx*CC + wc0)*CC;
    const unsigned short* wTlp = wT_lo + ((size_t)widx*CC + wc0)*CC;
    const bool split3 = (widx < 2);            // theta/phi 3-pass; g 1-pass

    const int wv   = tid >> 6;
    const int lane = tid & 63;
    const int quad = lane >> 4;
    const int l15  = lane & 15;
    // frag-ordered A base: row-tile rb*4+wv, per-lane 16B inside each 1KB frag
    const size_t afbase = ((size_t)(rb*4 + wv)*8)*512 + (size_t)lane*8;
    const unsigned short* axh = x_hi + afbase;
    const unsigned short* axl = x_lo + afbase;

    float4v acc[4];
    #pragma unroll
    for (int nf = 0; nf < 4; ++nf) acc[nf] = (float4v){0.f,0.f,0.f,0.f};

    for (int h = 0; h < 2; ++h) {
        __syncthreads();
        {   // stage pre-split W^T tile [64 cols][128 k] (pure copy)
            const int j    = tid & 63;
            const int kseg = tid >> 6;
            const size_t base = (size_t)j*CC + h*128 + kseg*32;
            const unsigned short* sh = wThp + base;
            unsigned short* dh = &wt_hi[j*136 + kseg*32];
            #pragma unroll
            for (int u = 0; u < 4; ++u)
                *(uint4*)(dh + u*8) = *(const uint4*)(sh + u*8);
            if (split3) {
                const unsigned short* sl = wTlp + base;
                unsigned short* dl = &wt_lo[j*136 + kseg*32];
                #pragma unroll
                for (int u = 0; u < 4; ++u)
                    *(uint4*)(dl + u*8) = *(const uint4*)(sl + u*8);
            }
        }
        __syncthreads();

        #pragma unroll
        for (int ks = 0; ks < 4; ++ks) {
            short8 a_hi = *(const short8*)(axh + (size_t)(h*4 + ks)*512);
            short8 a_lo;
            if (split3) a_lo = *(const short8*)(axl + (size_t)(h*4 + ks)*512);
            #pragma unroll
            for (int nf = 0; nf < 4; ++nf) {
                const int wrow = nf*16 + l15;
                short8 b_hi = *(const short8*)&wt_hi[wrow*136 + ks*32 + quad*8];
                acc[nf] = __builtin_amdgcn_mfma_f32_16x16x32_bf16(a_hi, b_hi, acc[nf], 0,0,0);
                if (split3) {
                    short8 b_lo = *(const short8*)&wt_lo[wrow*136 + ks*32 + quad*8];
                    acc[nf] = __builtin_amdgcn_mfma_f32_16x16x32_bf16(a_hi, b_lo, acc[nf], 0,0,0);
                    acc[nf] = __builtin_amdgcn_mfma_f32_16x16x32_bf16(a_lo, b_hi, acc[nf], 0,0,0);
                }
            }
        }
    }

    const int rowbase = r0 + wv*16 + quad*4;
    if (widx == 0) {                           // theta: unpooled, fp16 single
        #pragma unroll
        for (int nf = 0; nf < 4; ++nf) {
            const int c = wc0 + nf*16 + l15;
            #pragma unroll
            for (int r = 0; r < 4; ++r)
                th[(size_t)(rowbase + r)*CC + c] = f2h(acc[nf][r]);
        }
    } else if (widx == 1) {                    // phi: pool row pairs, fp16
        #pragma unroll
        for (int nf = 0; nf < 4; ++nf) {
            const int c = wc0 + nf*16 + l15;
            #pragma unroll
            for (int rp = 0; rp < 2; ++rp) {
                float v = fmaxf(acc[nf][2*rp], acc[nf][2*rp+1]);
                const int prow = rowbase/2 + rp;   // rowbase even -> exact
                ph[(size_t)prow*CC + c] = f2h(v);
            }
        }
    } else {                                   // g: pool, bf16, FRAG ORDER
        #pragma unroll
        for (int nf = 0; nf < 4; ++nf) {
            const int c = wc0 + nf*16 + l15;
            const int ct = c >> 4;             // col-tile 0..15
            const int c15 = c & 15;
            #pragma unroll
            for (int rp = 0; rp < 2; ++rp) {
                float v = fmaxf(acc[nf][2*rp], acc[nf][2*rp+1]);
                const int prow = rowbase/2 + rp;
                const int b  = prow >> 11;
                const int m  = prow & 2047;    // key index within batch
                const int kt = m >> 5;         // 32-key tile
                const int km = m & 31;
                const int lane_t = (km >> 3)*16 + c15;
                const int j = km & 7;
                g_f[(((size_t)(b*64 + kt)*16 + ct)*64 + lane_t)*8 + j] = f2bf(v);
            }
        }
    }
}

// ---------------------------------------------------------------------------
// phimean: per-batch column mean of phi; 512 blocks (32 rows each).
// ---------------------------------------------------------------------------
__global__ void phimean_kernel(const unsigned short* __restrict__ ph,
                               float* __restrict__ phbar)
{
    const int b = blockIdx.x >> 6, chunk = blockIdx.x & 63;
    const int c = threadIdx.x;
    const size_t base = ((size_t)b*MM + chunk*32)*CC + c;
    float s = 0.f;
    for (int r = 0; r < 32; ++r) s += h2f(ph[base + (size_t)r*CC]);
    atomicAdd(&phbar[b*CC + c], s * (1.0f/MM));
}

// ---------------------------------------------------------------------------
// attn_kernel v15 (verified 103us @ R11): coalesced staging, frag-ordered g,
// batch<->XCD affinity, 2 barriers, single s_p. UNCHANGED.
// ---------------------------------------------------------------------------
__global__ __launch_bounds__(256, 3) void attn_kernel(
    const float* __restrict__ x,
    const unsigned short* __restrict__ th,
    const unsigned short* __restrict__ ph,
    const unsigned short* __restrict__ g_f,
    const float* __restrict__ phbar,
    float* __restrict__ out)
{
    __shared__ unsigned short s_ph[2][32*264]; // phi dbuf fp16, padded rows
    __shared__ unsigned short s_p[4][16*40];   // P: [src wave][16 q][32 k pad 40]
    __shared__ float          s_l[64];         // final row sums

    const int tid  = threadIdx.x;
    const int bb   = blockIdx.x & 7;           // batch == XCD (L2 affinity)
    const int qt   = blockIdx.x >> 3;          // q-tile within batch
    const int q0   = bb*NN + qt*64;
    const int b    = bb;
    const int wv   = tid >> 6;
    const int lane = tid & 63;
    const int quad = lane >> 4;
    const int l15  = lane & 15;

    // coalesced staging geometry: instr u, thread tid owns chunk u*256+tid
    const size_t phbase = (size_t)b * MM * CC;
    const unsigned short* stsrc = ph + phbase + (size_t)tid*8;
    const int ldsbase = (tid >> 5)*264 + (tid & 31)*8;

    // theta A-frags (fp16, single) for this wave's 16 rows
    half8 t_hi[8];
    {
        const unsigned short* bh = th + (size_t)(q0 + wv*16 + l15)*CC;
        #pragma unroll
        for (int ks = 0; ks < 8; ++ks)
            t_hi[ks] = *(const half8*)(bh + ks*32 + quad*8);
    }

    // per-row shift = theta . phibar (+128), moved to C-layout rows via shfl
    float sh128[4];
    {
        float sp = 0.f;
        #pragma unroll
        for (int ks = 0; ks < 8; ++ks) {
            const int k0 = ks*32 + quad*8;
            float4v m0 = *(const float4v*)&phbar[b*CC + k0];
            float4v m1 = *(const float4v*)&phbar[b*CC + k0 + 4];
            #pragma unroll
            for (int j = 0; j < 4; ++j) {
                sp += (float)t_hi[ks][j]   * m0[j];
                sp += (float)t_hi[ks][4+j] * m1[j];
            }
        }
        sp += __shfl_xor(sp, 16);
        sp += __shfl_xor(sp, 32);
        #pragma unroll
        for (int r = 0; r < 4; ++r)
            sh128[r] = __shfl(sp, quad*4 + r) + 128.f;
    }

    // O: all 64 block-queries x this wave's 64-col strip
    float4v O[4][4];
    #pragma unroll
    for (int rt = 0; rt < 4; ++rt)
        #pragma unroll
        for (int ct = 0; ct < 4; ++ct) O[rt][ct] = (float4v){0.f,0.f,0.f,0.f};
    float4v accl = (float4v){0.f,0.f,0.f,0.f};

    short8 ones;
    #pragma unroll
    for (int j = 0; j < 8; ++j) ones[j] = (short)0x3F80;   // bf16 1.0

    // frag-ordered g base (R9 win): per-lane 16B inside each 1KB frag
    const unsigned short* glf = g_f + (size_t)b*MM*CC + (size_t)lane*8;

    // prologue: stage tile 0 into buf 0 (coalesced)
    {
        #pragma unroll
        for (int u = 0; u < 4; ++u)
            *(uint4*)(&s_ph[0][ldsbase + u*2112]) =
                *(const uint4*)(stsrc + u*2048);
    }
    __syncthreads();

    for (int kt = 0; kt < 64; ++kt) {
        const int cur  = kt & 1;

        // issue next-tile phi loads early (coalesced; latency hides under S)
        uint4 stg[4];
        if (kt < 63) {
            const unsigned short* sn = stsrc + (size_t)(kt + 1)*8192;
            #pragma unroll
            for (int u = 0; u < 4; ++u)
                stg[u] = *(const uint4*)(sn + u*2048);
        }
        // this tile's g frags: ONE coalesced b128 per col-tile
        short8 gf[4];
        #pragma unroll
        for (int ct = 0; ct < 4; ++ct)
            gf[ct] = *(const short8*)(glf + (size_t)(kt*16 + wv*4 + ct)*512);

        // S = theta @ phi^T, 1-pass fp16, from current buffer
        float4v S0 = (float4v){0.f,0.f,0.f,0.f};
        float4v S1 = (float4v){0.f,0.f,0.f,0.f};
        #pragma unroll
        for (int ks = 0; ks < 8; ++ks) {
            half8 b0 = *(const half8*)&s_ph[cur][( 0 + l15)*264 + ks*32 + quad*8];
            half8 b1 = *(const half8*)&s_ph[cur][(16 + l15)*264 + ks*32 + quad*8];
            S0 = __builtin_amdgcn_mfma_f32_16x16x32_f16(t_hi[ks], b0, S0, 0,0,0);
            S1 = __builtin_amdgcn_mfma_f32_16x16x32_f16(t_hi[ks], b1, S1, 0,0,0);
        }

        // p = exp(clamp(S - shift, -85, 85)) -> bf16 into shared P
        unsigned short* pw = &s_p[wv][0];
        #pragma unroll
        for (int r = 0; r < 4; ++r) {
            float a0 = fminf(fmaxf(S0[r] - sh128[r], -85.f), 85.f);
            float a1 = fminf(fmaxf(S1[r] - sh128[r], -85.f), 85.f);
            pw[(quad*4 + r)*40 + l15]      = f2bf(__expf(a0));
            pw[(quad*4 + r)*40 + 16 + l15] = f2bf(__expf(a1));
        }
        asm volatile("s_waitcnt lgkmcnt(0)" ::: "memory");
        // own-row l accumulation (own s_p region; intra-wave wait only)
        short8 pown = *(const short8*)&s_p[wv][l15*40 + quad*8];
        accl = __builtin_amdgcn_mfma_f32_16x16x32_bf16(pown, ones, accl, 0,0,0);

        // write staged phi into the other buffer before the barrier
        if (kt < 63) {
            #pragma unroll
            for (int u = 0; u < 4; ++u)
                *(uint4*)(&s_ph[cur ^ 1][ldsbase + u*2112]) = stg[u];
        }
        __syncthreads();                       // P visible; next phi staged

        // PV: O[all 64 q][this wave's 64 cols] += P @ g
        #pragma unroll
        for (int rt = 0; rt < 4; ++rt) {
            short8 pA = *(const short8*)&s_p[rt][l15*40 + quad*8];
            #pragma unroll
            for (int ct = 0; ct < 4; ++ct)
                O[rt][ct] = __builtin_amdgcn_mfma_f32_16x16x32_bf16(pA, gf[ct], O[rt][ct], 0,0,0);
        }
        __syncthreads();                       // s_p reusable next iter
    }

    // broadcast row sums: wave wv owns l for queries wv*16..wv*16+15
    if (l15 == 0) {
        #pragma unroll
        for (int r = 0; r < 4; ++r) s_l[wv*16 + quad*4 + r] = accl[r];
    }
    __syncthreads();

    // epilogue: y = O/l, out = x + y  (wave wv writes cols wv*64..wv*64+63)
    #pragma unroll
    for (int rt = 0; rt < 4; ++rt) {
        #pragma unroll
        for (int r = 0; r < 4; ++r) {
            const int row = q0 + rt*16 + quad*4 + r;
            const float rl = 1.0f / s_l[rt*16 + quad*4 + r];
            #pragma unroll
            for (int ct = 0; ct < 4; ++ct) {
                const int c = wv*64 + ct*16 + l15;
                const size_t idx = (size_t)row*CC + c;
                out[idx] = x[idx] + O[rt][ct][r] * rl;
            }
        }
    }
}

// ---------------------------------------------------------------------------
extern "C" void kernel_launch(void* const* d_in, const int* in_sizes, int n_in,
                              void* d_out, int out_size, void* d_ws, size_t ws_size,
                              hipStream_t stream) {
    const float* x       = (const float*)d_in[0];
    const float* w_theta = (const float*)d_in[1];
    const float* w_phi   = (const float*)d_in[2];
    const float* w_g     = (const float*)d_in[3];
    float* out = (float*)d_out;

    // workspace (~51.2 MB)
    unsigned short* th    = (unsigned short*)d_ws;                 // fp16 16.78 MB
    unsigned short* ph    = th    + (size_t)NROWS*CC;              // fp16  8.39 MB
    unsigned short* g_f   = ph    + (size_t)PROWS*CC;              // bf16  8.39 MB (frag order)
    unsigned short* x_hi  = g_f   + (size_t)PROWS*CC;              // bf16  8.39 MB (frag order)
    unsigned short* x_lo  = x_hi  + (size_t)NROWS*CC;              // bf16  8.39 MB (frag order)
    unsigned short* wT_hi = x_lo  + (size_t)NROWS*CC;              // bf16  0.39 MB
    unsigned short* wT_lo = wT_hi + (size_t)3*CC*CC;               // bf16  0.39 MB
    float*          phbar = (float*)(wT_lo + (size_t)3*CC*CC);     // fp32  8 KB

    hipMemsetAsync(phbar, 0, BB*CC*sizeof(float), stream);
    xsplit_kernel<<<NROWS/16, 256, 0, stream>>>(x, x_hi, x_lo);
    wsplit_kernel<<<dim3(4,4,3), 256, 0, stream>>>(w_theta, w_phi, w_g, wT_hi, wT_lo);
    proj_kernel<<<6144, 256, 0, stream>>>(x_hi, x_lo, wT_hi, wT_lo, th, ph, g_f);
    phimean_kernel<<<512, 256, 0, stream>>>(ph, phbar);
    attn_kernel<<<NROWS/64, 256, 0, stream>>>(x, th, ph, g_f, phbar, out);
}

// Round 15
// 249.270 us; speedup vs baseline: 1.2191x; 1.0399x over previous
//
#include <hip/hip_runtime.h>
#include <stdint.h>

// Problem constants (fixed by the reference): B=8, H=W=64, C=256
#define CC 256
#define NN 4096           // H*W
#define MM 2048           // NN/2 (pooled)
#define BB 8
#define NROWS (BB*NN)     // 32768 query rows
#define PROWS (BB*MM)     // 16384 pooled rows

typedef __attribute__((ext_vector_type(8))) short    short8;   // 8 bf16
typedef __attribute__((ext_vector_type(8))) _Float16 half8;    // 8 fp16
typedef __attribute__((ext_vector_type(4))) float    float4v;

__device__ __forceinline__ unsigned short f2bf(float f) {
    unsigned int u = __float_as_uint(f);
    u += 0x7fffu + ((u >> 16) & 1u);
    return (unsigned short)(u >> 16);
}
__device__ __forceinline__ float bf2f(unsigned short h) {
    return __uint_as_float(((unsigned int)h) << 16);
}
__device__ __forceinline__ unsigned short f2h(float f) {
    union { _Float16 h; unsigned short u; } cv; cv.h = (_Float16)f; return cv.u;
}
__device__ __forceinline__ float h2f(unsigned short u) {
    union { _Float16 h; unsigned short u; } cv; cv.u = u; return (float)cv.h;
}

// ---------------------------------------------------------------------------
// xsplit v2 (verified R14): x -> x_hi/x_lo in MFMA A-FRAGMENT ORDER.
// ---------------------------------------------------------------------------
__global__ __launch_bounds__(256) void xsplit_kernel(
    const float* __restrict__ x,
    unsigned short* __restrict__ x_hi,
    unsigned short* __restrict__ x_lo)
{
    const int rt   = blockIdx.x;               // row-tile 0..2047
    const int tid  = threadIdx.x;
    const int wv   = tid >> 6;
    const int lane = tid & 63;
    const int quad = lane >> 4;
    const int l15  = lane & 15;
    const int row  = rt*16 + l15;
    #pragma unroll
    for (int kk = 0; kk < 2; ++kk) {
        const int ks = wv*2 + kk;              // 0..7
        const int k0 = ks*32 + quad*8;
        float4v a0 = *(const float4v*)(x + (size_t)row*CC + k0);
        float4v a1 = *(const float4v*)(x + (size_t)row*CC + k0 + 4);
        short8 h, l;
        #pragma unroll
        for (int j = 0; j < 4; ++j) {
            unsigned short h0 = f2bf(a0[j]);
            h[j]   = (short)h0; l[j]   = (short)f2bf(a0[j] - bf2f(h0));
            unsigned short h1 = f2bf(a1[j]);
            h[4+j] = (short)h1; l[4+j] = (short)f2bf(a1[j] - bf2f(h1));
        }
        const size_t o = ((size_t)rt*8 + ks)*512 + (size_t)lane*8;
        *(short8*)(x_hi + o) = h;
        *(short8*)(x_lo + o) = l;
    }
}

// ---------------------------------------------------------------------------
// wsplit v2: weights -> B-FRAGMENT-ORDERED wTf_hi/wTf_lo.
//   frag (widx, ct, ks) = 1KB: lane (quad,l15) holds w^T[c=ct*16+l15]
//   [k=ks*32+quad*8 .. +7] = w[k][c], split hi/lo bf16.
//   Same values as the old LDS-staged wT: proj numerics bit-identical.
// ---------------------------------------------------------------------------
__global__ void wsplit_kernel(const float* __restrict__ w_theta,
                              const float* __restrict__ w_phi,
                              const float* __restrict__ w_g,
                              unsigned short* __restrict__ wTf_hi,
                              unsigned short* __restrict__ wTf_lo)
{
    const int widx = blockIdx.z;               // 0..2
    const int ct   = blockIdx.x;               // col-tile 0..15
    const float* w = (widx == 0) ? w_theta : (widx == 1) ? w_phi : w_g;
    const int tid  = threadIdx.x;
    const int wv   = tid >> 6;
    const int lane = tid & 63;
    const int quad = lane >> 4;
    const int l15  = lane & 15;
    const int c    = ct*16 + l15;
    #pragma unroll
    for (int kk = 0; kk < 2; ++kk) {
        const int ks = wv*2 + kk;              // 0..7
        short8 h, l;
        #pragma unroll
        for (int j = 0; j < 8; ++j) {
            float v = w[(size_t)(ks*32 + quad*8 + j)*CC + c];
            unsigned short hh = f2bf(v);
            h[j] = (short)hh;
            l[j] = (short)f2bf(v - bf2f(hh));
        }
        const size_t o = ((size_t)(widx*16 + ct)*8 + ks)*512 + (size_t)lane*8;
        *(short8*)(wTf_hi + o) = h;
        *(short8*)(wTf_lo + o) = l;
    }
}

// ---------------------------------------------------------------------------
// proj_kernel v10: NO LDS, NO BARRIERS. A-frags from frag-ordered x_hi/x_lo
// (R14), B-frags from frag-ordered wTf (this round) — every operand load is
// one coalesced b128 from L1/L2-resident memory. Same MFMA order as v9
// (kc outer = h*4+ks; per (kc,nf): a_hi*b_hi, a_hi*b_lo, a_lo*b_hi) ->
// numerics bit-identical (absmax tripwire 0.0703125).
// ---------------------------------------------------------------------------
__global__ __launch_bounds__(256, 4) void proj_kernel(
    const unsigned short* __restrict__ x_hi,
    const unsigned short* __restrict__ x_lo,
    const unsigned short* __restrict__ wTf_hi,
    const unsigned short* __restrict__ wTf_lo,
    unsigned short* __restrict__ th,
    unsigned short* __restrict__ ph,
    unsigned short* __restrict__ g_f)
{
    const int tid  = threadIdx.x;
    const int rb   = blockIdx.x & 511;         // row-block (XCD = rb%8)
    const int cv   = blockIdx.x >> 9;          // 0..11 col-variant
    const int r0   = rb * 64;
    const int widx = cv >> 2;
    const int wc0  = (cv & 3) * 64;
    const int ct0  = (cv & 3) * 4;             // first col-tile of this block
    const bool split3 = (widx < 2);            // theta/phi 3-pass; g 1-pass

    const int wv   = tid >> 6;
    const int lane = tid & 63;
    const int quad = lane >> 4;
    const int l15  = lane & 15;

    // frag-ordered A base: row-tile rb*4+wv, per-lane 16B inside each 1KB frag
    const unsigned short* axh = x_hi + ((size_t)(rb*4 + wv)*8)*512 + (size_t)lane*8;
    const unsigned short* axl = x_lo + ((size_t)(rb*4 + wv)*8)*512 + (size_t)lane*8;
    // frag-ordered B base for this weight
    const unsigned short* wfh = wTf_hi + ((size_t)widx*16*8)*512 + (size_t)lane*8;
    const unsigned short* wfl = wTf_lo + ((size_t)widx*16*8)*512 + (size_t)lane*8;

    float4v acc[4];
    #pragma unroll
    for (int nf = 0; nf < 4; ++nf) acc[nf] = (float4v){0.f,0.f,0.f,0.f};

    #pragma unroll
    for (int kc = 0; kc < 8; ++kc) {
        short8 a_hi = *(const short8*)(axh + (size_t)kc*512);
        short8 a_lo;
        if (split3) a_lo = *(const short8*)(axl + (size_t)kc*512);
        #pragma unroll
        for (int nf = 0; nf < 4; ++nf) {
            const size_t bo = ((size_t)(ct0 + nf)*8 + kc)*512;
            short8 b_hi = *(const short8*)(wfh + bo);
            acc[nf] = __builtin_amdgcn_mfma_f32_16x16x32_bf16(a_hi, b_hi, acc[nf], 0,0,0);
            if (split3) {
                short8 b_lo = *(const short8*)(wfl + bo);
                acc[nf] = __builtin_amdgcn_mfma_f32_16x16x32_bf16(a_hi, b_lo, acc[nf], 0,0,0);
                acc[nf] = __builtin_amdgcn_mfma_f32_16x16x32_bf16(a_lo, b_hi, acc[nf], 0,0,0);
            }
        }
    }

    const int rowbase = r0 + wv*16 + quad*4;
    if (widx == 0) {                           // theta: unpooled, fp16 single
        #pragma unroll
        for (int nf = 0; nf < 4; ++nf) {
            const int c = wc0 + nf*16 + l15;
            #pragma unroll
            for (int r = 0; r < 4; ++r)
                th[(size_t)(rowbase + r)*CC + c] = f2h(acc[nf][r]);
        }
    } else if (widx == 1) {                    // phi: pool row pairs, fp16
        #pragma unroll
        for (int nf = 0; nf < 4; ++nf) {
            const int c = wc0 + nf*16 + l15;
            #pragma unroll
            for (int rp = 0; rp < 2; ++rp) {
                float v = fmaxf(acc[nf][2*rp], acc[nf][2*rp+1]);
                const int prow = rowbase/2 + rp;   // rowbase even -> exact
                ph[(size_t)prow*CC + c] = f2h(v);
            }
        }
    } else {                                   // g: pool, bf16, FRAG ORDER
        #pragma unroll
        for (int nf = 0; nf < 4; ++nf) {
            const int c = wc0 + nf*16 + l15;
            const int ct = c >> 4;             // col-tile 0..15
            const int c15 = c & 15;
            #pragma unroll
            for (int rp = 0; rp < 2; ++rp) {
                float v = fmaxf(acc[nf][2*rp], acc[nf][2*rp+1]);
                const int prow = rowbase/2 + rp;
                const int b  = prow >> 11;
                const int m  = prow & 2047;    // key index within batch
                const int kt = m >> 5;         // 32-key tile
                const int km = m & 31;
                const int lane_t = (km >> 3)*16 + c15;
                const int j = km & 7;
                g_f[(((size_t)(b*64 + kt)*16 + ct)*64 + lane_t)*8 + j] = f2bf(v);
            }
        }
    }
}

// ---------------------------------------------------------------------------
// phimean: per-batch column mean of phi; 512 blocks (32 rows each).
// ---------------------------------------------------------------------------
__global__ void phimean_kernel(const unsigned short* __restrict__ ph,
                               float* __restrict__ phbar)
{
    const int b = blockIdx.x >> 6, chunk = blockIdx.x & 63;
    const int c = threadIdx.x;
    const size_t base = ((size_t)b*MM + chunk*32)*CC + c;
    float s = 0.f;
    for (int r = 0; r < 32; ++r) s += h2f(ph[base + (size_t)r*CC]);
    atomicAdd(&phbar[b*CC + c], s * (1.0f/MM));
}

// ---------------------------------------------------------------------------
// attn_kernel v15 (verified 103us @ R11): coalesced staging, frag-ordered g,
// batch<->XCD affinity, 2 barriers, single s_p. UNCHANGED.
// ---------------------------------------------------------------------------
__global__ __launch_bounds__(256, 3) void attn_kernel(
    const float* __restrict__ x,
    const unsigned short* __restrict__ th,
    const unsigned short* __restrict__ ph,
    const unsigned short* __restrict__ g_f,
    const float* __restrict__ phbar,
    float* __restrict__ out)
{
    __shared__ unsigned short s_ph[2][32*264]; // phi dbuf fp16, padded rows
    __shared__ unsigned short s_p[4][16*40];   // P: [src wave][16 q][32 k pad 40]
    __shared__ float          s_l[64];         // final row sums

    const int tid  = threadIdx.x;
    const int bb   = blockIdx.x & 7;           // batch == XCD (L2 affinity)
    const int qt   = blockIdx.x >> 3;          // q-tile within batch
    const int q0   = bb*NN + qt*64;
    const int b    = bb;
    const int wv   = tid >> 6;
    const int lane = tid & 63;
    const int quad = lane >> 4;
    const int l15  = lane & 15;

    // coalesced staging geometry: instr u, thread tid owns chunk u*256+tid
    const size_t phbase = (size_t)b * MM * CC;
    const unsigned short* stsrc = ph + phbase + (size_t)tid*8;
    const int ldsbase = (tid >> 5)*264 + (tid & 31)*8;

    // theta A-frags (fp16, single) for this wave's 16 rows
    half8 t_hi[8];
    {
        const unsigned short* bh = th + (size_t)(q0 + wv*16 + l15)*CC;
        #pragma unroll
        for (int ks = 0; ks < 8; ++ks)
            t_hi[ks] = *(const half8*)(bh + ks*32 + quad*8);
    }

    // per-row shift = theta . phibar (+128), moved to C-layout rows via shfl
    float sh128[4];
    {
        float sp = 0.f;
        #pragma unroll
        for (int ks = 0; ks < 8; ++ks) {
            const int k0 = ks*32 + quad*8;
            float4v m0 = *(const float4v*)&phbar[b*CC + k0];
            float4v m1 = *(const float4v*)&phbar[b*CC + k0 + 4];
            #pragma unroll
            for (int j = 0; j < 4; ++j) {
                sp += (float)t_hi[ks][j]   * m0[j];
                sp += (float)t_hi[ks][4+j] * m1[j];
            }
        }
        sp += __shfl_xor(sp, 16);
        sp += __shfl_xor(sp, 32);
        #pragma unroll
        for (int r = 0; r < 4; ++r)
            sh128[r] = __shfl(sp, quad*4 + r) + 128.f;
    }

    // O: all 64 block-queries x this wave's 64-col strip
    float4v O[4][4];
    #pragma unroll
    for (int rt = 0; rt < 4; ++rt)
        #pragma unroll
        for (int ct = 0; ct < 4; ++ct) O[rt][ct] = (float4v){0.f,0.f,0.f,0.f};
    float4v accl = (float4v){0.f,0.f,0.f,0.f};

    short8 ones;
    #pragma unroll
    for (int j = 0; j < 8; ++j) ones[j] = (short)0x3F80;   // bf16 1.0

    // frag-ordered g base (R9 win): per-lane 16B inside each 1KB frag
    const unsigned short* glf = g_f + (size_t)b*MM*CC + (size_t)lane*8;

    // prologue: stage tile 0 into buf 0 (coalesced)
    {
        #pragma unroll
        for (int u = 0; u < 4; ++u)
            *(uint4*)(&s_ph[0][ldsbase + u*2112]) =
                *(const uint4*)(stsrc + u*2048);
    }
    __syncthreads();

    for (int kt = 0; kt < 64; ++kt) {
        const int cur  = kt & 1;

        // issue next-tile phi loads early (coalesced; latency hides under S)
        uint4 stg[4];
        if (kt < 63) {
            const unsigned short* sn = stsrc + (size_t)(kt + 1)*8192;
            #pragma unroll
            for (int u = 0; u < 4; ++u)
                stg[u] = *(const uint4*)(sn + u*2048);
        }
        // this tile's g frags: ONE coalesced b128 per col-tile
        short8 gf[4];
        #pragma unroll
        for (int ct = 0; ct < 4; ++ct)
            gf[ct] = *(const short8*)(glf + (size_t)(kt*16 + wv*4 + ct)*512);

        // S = theta @ phi^T, 1-pass fp16, from current buffer
        float4v S0 = (float4v){0.f,0.f,0.f,0.f};
        float4v S1 = (float4v){0.f,0.f,0.f,0.f};
        #pragma unroll
        for (int ks = 0; ks < 8; ++ks) {
            half8 b0 = *(const half8*)&s_ph[cur][( 0 + l15)*264 + ks*32 + quad*8];
            half8 b1 = *(const half8*)&s_ph[cur][(16 + l15)*264 + ks*32 + quad*8];
            S0 = __builtin_amdgcn_mfma_f32_16x16x32_f16(t_hi[ks], b0, S0, 0,0,0);
            S1 = __builtin_amdgcn_mfma_f32_16x16x32_f16(t_hi[ks], b1, S1, 0,0,0);
        }

        // p = exp(clamp(S - shift, -85, 85)) -> bf16 into shared P
        unsigned short* pw = &s_p[wv][0];
        #pragma unroll
        for (int r = 0; r < 4; ++r) {
            float a0 = fminf(fmaxf(S0[r] - sh128[r], -85.f), 85.f);
            float a1 = fminf(fmaxf(S1[r] - sh128[r], -85.f), 85.f);
            pw[(quad*4 + r)*40 + l15]      = f2bf(__expf(a0));
            pw[(quad*4 + r)*40 + 16 + l15] = f2bf(__expf(a1));
        }
        asm volatile("s_waitcnt lgkmcnt(0)" ::: "memory");
        // own-row l accumulation (own s_p region; intra-wave wait only)
        short8 pown = *(const short8*)&s_p[wv][l15*40 + quad*8];
        accl = __builtin_amdgcn_mfma_f32_16x16x32_bf16(pown, ones, accl, 0,0,0);

        // write staged phi into the other buffer before the barrier
        if (kt < 63) {
            #pragma unroll
            for (int u = 0; u < 4; ++u)
                *(uint4*)(&s_ph[cur ^ 1][ldsbase + u*2112]) = stg[u];
        }
        __syncthreads();                       // P visible; next phi staged

        // PV: O[all 64 q][this wave's 64 cols] += P @ g
        #pragma unroll
        for (int rt = 0; rt < 4; ++rt) {
            short8 pA = *(const short8*)&s_p[rt][l15*40 + quad*8];
            #pragma unroll
            for (int ct = 0; ct < 4; ++ct)
                O[rt][ct] = __builtin_amdgcn_mfma_f32_16x16x32_bf16(pA, gf[ct], O[rt][ct], 0,0,0);
        }
        __syncthreads();                       // s_p reusable next iter
    }

    // broadcast row sums: wave wv owns l for queries wv*16..wv*16+15
    if (l15 == 0) {
        #pragma unroll
        for (int r = 0; r < 4; ++r) s_l[wv*16 + quad*4 + r] = accl[r];
    }
    __syncthreads();

    // epilogue: y = O/l, out = x + y  (wave wv writes cols wv*64..wv*64+63)
    #pragma unroll
    for (int rt = 0; rt < 4; ++rt) {
        #pragma unroll
        for (int r = 0; r < 4; ++r) {
            const int row = q0 + rt*16 + quad*4 + r;
            const float rl = 1.0f / s_l[rt*16 + quad*4 + r];
            #pragma unroll
            for (int ct = 0; ct < 4; ++ct) {
                const int c = wv*64 + ct*16 + l15;
                const size_t idx = (size_t)row*CC + c;
                out[idx] = x[idx] + O[rt][ct][r] * rl;
            }
        }
    }
}

// ---------------------------------------------------------------------------
extern "C" void kernel_launch(void* const* d_in, const int* in_sizes, int n_in,
                              void* d_out, int out_size, void* d_ws, size_t ws_size,
                              hipStream_t stream) {
    const float* x       = (const float*)d_in[0];
    const float* w_theta = (const float*)d_in[1];
    const float* w_phi   = (const float*)d_in[2];
    const float* w_g     = (const float*)d_in[3];
    float* out = (float*)d_out;

    // workspace (~51.2 MB)
    unsigned short* th    = (unsigned short*)d_ws;                 // fp16 16.78 MB
    unsigned short* ph    = th    + (size_t)NROWS*CC;              // fp16  8.39 MB
    unsigned short* g_f   = ph    + (size_t)PROWS*CC;              // bf16  8.39 MB (frag order)
    unsigned short* x_hi  = g_f   + (size_t)PROWS*CC;              // bf16  8.39 MB (frag order)
    unsigned short* x_lo  = x_hi  + (size_t)NROWS*CC;              // bf16  8.39 MB (frag order)
    unsigned short* wTf_hi = x_lo  + (size_t)NROWS*CC;             // bf16  0.39 MB (frag order)
    unsigned short* wTf_lo = wTf_hi + (size_t)3*CC*CC;             // bf16  0.39 MB (frag order)
    float*          phbar = (float*)(wTf_lo + (size_t)3*CC*CC);    // fp32  8 KB

    hipMemsetAsync(phbar, 0, BB*CC*sizeof(float), stream);
    xsplit_kernel<<<NROWS/16, 256, 0, stream>>>(x, x_hi, x_lo);
    wsplit_kernel<<<dim3(16,1,3), 256, 0, stream>>>(w_theta, w_phi, w_g, wTf_hi, wTf_lo);
    proj_kernel<<<6144, 256, 0, stream>>>(x_hi, x_lo, wTf_hi, wTf_lo, th, ph, g_f);
    phimean_kernel<<<512, 256, 0, stream>>>(ph, phbar);
    attn_kernel<<<NROWS/64, 256, 0, stream>>>(x, th, ph, g_f, phbar, out);
}